// Round 8
// baseline (580.241 us; speedup 1.0000x reference)
//
#include <hip/hip_runtime.h>
#include <math.h>

#define EMB 256
#define HEADS 8
#define HD 32
#define BATCH 2
#define SEQ 4096
#define QSCALE 0.25504672075827703f   // (1/sqrt(32)) * log2(e)  -- exp2-folded softmax scale

typedef __attribute__((ext_vector_type(8))) _Float16 f16x8;
typedef __attribute__((ext_vector_type(4))) _Float16 f16x4;
typedef __attribute__((ext_vector_type(2))) __fp16 fp16x2_native;
typedef __attribute__((ext_vector_type(4))) float f32x4;
typedef unsigned int uint_t;

__device__ __forceinline__ uint_t pk16(float a, float b) {
    union { fp16x2_native h; uint_t u; } cv;
    cv.h = __builtin_amdgcn_cvt_pkrtz(a, b);
    return cv.u;
}

#define MFMA16(A, B, C) __builtin_amdgcn_mfma_f32_16x16x32_f16(A, B, C, 0, 0, 0)

// ---------------------------------------------------------------------------
// Prep 1: query fp32 -> Xh/Xl fp16 hi/lo split.  [r=b*4096+s][256]
// ---------------------------------------------------------------------------
__global__ __launch_bounds__(256) void prep_x_kernel(
    const float* __restrict__ q, _Float16* __restrict__ Xh, _Float16* __restrict__ Xl)
{
    const int i = (blockIdx.x * 256 + threadIdx.x) * 8;
    float4 v0 = *(const float4*)(q + i);
    float4 v1 = *(const float4*)(q + i + 4);
    float xs[8] = {v0.x, v0.y, v0.z, v0.w, v1.x, v1.y, v1.z, v1.w};
    f16x8 hv, lv;
    #pragma unroll
    for (int j = 0; j < 8; j++) {
        _Float16 h = (_Float16)xs[j];
        hv[j] = h;
        lv[j] = (_Float16)(xs[j] - (float)h);
    }
    *(f16x8*)(Xh + i) = hv;
    *(f16x8*)(Xl + i) = lv;
}

// ---------------------------------------------------------------------------
// Prep 2: weights -> transposed fp16 hi/lo.
//   Wth/Wtl: [p][h][e=32][d=256], QSCALE folded into p==0 (Wq)
//   WoTh/WoTl: [o=256][he=256]
// ---------------------------------------------------------------------------
__global__ __launch_bounds__(256) void prep_w_kernel(
    const float* __restrict__ wq, const float* __restrict__ wk,
    const float* __restrict__ wv, const float* __restrict__ wo,
    _Float16* __restrict__ Wth, _Float16* __restrict__ Wtl,
    _Float16* __restrict__ WoTh, _Float16* __restrict__ WoTl)
{
    for (int t = blockIdx.x * 256 + threadIdx.x; t < 262144; t += 256 * 256) {
        if (t < 196608) {
            int d = t & 255, e = (t >> 8) & 31, ph = t >> 13;
            int p = ph >> 3, h = ph & 7;
            const float* w = (p == 0) ? wq : (p == 1 ? wk : wv);
            float val = w[h * 8192 + d * 32 + e] * ((p == 0) ? QSCALE : 1.0f);
            _Float16 hi = (_Float16)val;
            Wth[t] = hi;
            Wtl[t] = (_Float16)(val - (float)hi);
        } else {
            int t2 = t - 196608;
            int he = t2 & 255, o = t2 >> 8;
            float val = wo[(he >> 5) * 8192 + (he & 31) * 256 + o];
            _Float16 hi = (_Float16)val;
            WoTh[t2] = hi;
            WoTl[t2] = (_Float16)(val - (float)hi);
        }
    }
}

// ---------------------------------------------------------------------------
// Kernel 1: QKV projection as MFMA GEMM, no LDS staging of operands.
// grid (128, 24): x = 64-row tile (wave = 16 rows), y = p*8+h.
// D[s][e] = Xh*Wh + Xl*Wh + Xh*Wl   (fp32-grade via hi/lo split)
// Q/K: LDS-staged 64B-row writes.  V: direct VT[e][s] f16x4 writes.
// ---------------------------------------------------------------------------
__global__ __launch_bounds__(256) void qkv_gemm_kernel(
    const _Float16* __restrict__ Xh, const _Float16* __restrict__ Xl,
    const _Float16* __restrict__ Wth, const _Float16* __restrict__ Wtl,
    _Float16* __restrict__ Qf, _Float16* __restrict__ Kf, _Float16* __restrict__ VT)
{
    __shared__ _Float16 st[4][16][32];
    const int t = threadIdx.x, w = t >> 6, l = t & 63, lo4 = l & 15, g = l >> 4;
    const int tile = blockIdx.x, ph = blockIdx.y, p = ph >> 3, h = ph & 7;
    const int r0 = tile * 64 + w * 16;
    const int b = (tile * 64) >> 12;
    const int s_base = (tile * 64) & (SEQ - 1);
    const int hb = h * BATCH + b;

    f16x8 Ah[8], Al[8];
    const size_t xoff = (size_t)(r0 + lo4) * 256 + g * 8;
    #pragma unroll
    for (int kc = 0; kc < 8; kc++) {
        Ah[kc] = *(const f16x8*)(Xh + xoff + kc * 32);
        Al[kc] = *(const f16x8*)(Xl + xoff + kc * 32);
    }

    f32x4 D[2];
    #pragma unroll
    for (int ct = 0; ct < 2; ct++) {
        f32x4 acc = {0.f, 0.f, 0.f, 0.f};
        const size_t woff = (size_t)(ph * 32 + ct * 16 + lo4) * 256 + g * 8;
        #pragma unroll
        for (int kc = 0; kc < 8; kc++) {
            f16x8 Bh = *(const f16x8*)(Wth + woff + kc * 32);
            f16x8 Bl = *(const f16x8*)(Wtl + woff + kc * 32);
            acc = MFMA16(Ah[kc], Bh, acc);
            acc = MFMA16(Al[kc], Bh, acc);
            acc = MFMA16(Ah[kc], Bl, acc);
        }
        D[ct] = acc;
    }

    if (p < 2) {
        #pragma unroll
        for (int ct = 0; ct < 2; ct++)
            #pragma unroll
            for (int r = 0; r < 4; r++)
                st[w][g * 4 + r][ct * 16 + lo4] = (_Float16)D[ct][r];
        __syncthreads();
        _Float16* dst = (p == 0) ? Qf : Kf;
        const int rl = t >> 2, e8 = (t & 3) * 8;   // rl = 0..63 local row
        *(f16x8*)(dst + ((size_t)hb * SEQ + s_base + rl) * HD + e8) =
            *(f16x8*)&st[rl >> 4][rl & 15][e8];
    } else {
        #pragma unroll
        for (int ct = 0; ct < 2; ct++) {
            f16x4 v;
            #pragma unroll
            for (int r = 0; r < 4; r++) v[r] = (_Float16)D[ct][r];
            *(f16x4*)(VT + ((size_t)hb * HD + ct * 16 + lo4) * SEQ + s_base + w * 16 + g * 4) = v;
        }
    }
}

// ---------------------------------------------------------------------------
// Kernel 2: fused attention, two-pass no-max softmax (exp2-domain), fp16 MFMA.
// Round-15: round-7 wave-split structure (block = 64 q-rows, wave = 16 rows,
// full k-sweep per wave, no LDS / no lred / no Hred) + ONE change: a raw
// s_barrier every 4 c-iterations in both passes.  Round 7 regressed because
// unsynchronized waves drift apart and each independently streams the full
// 768 KB K/V from HBM (4x logical reads -> 566us).  The raw barrier
// (__builtin_amdgcn_s_barrier, NO vmcnt drain -- unlike __syncthreads,
// whose forced store-drain regressed rounds 1-5) keeps the 4 waves of the
// CU within a <=4-iteration window (~16 KB of K+V, fits 32 KB L1), so the
// first wave's miss fills L1 and the other three HIT -> 1x K/V read per
// block, half of round-0's total.
// ---------------------------------------------------------------------------
__global__ __launch_bounds__(256) void attn_kernel(
    const _Float16* __restrict__ Qf, const _Float16* __restrict__ Kf,
    const _Float16* __restrict__ VT,
    float* __restrict__ attn_out,     // [hb][q][k]
    _Float16* __restrict__ heads)     // [hb][q][e] fp16
{
    const int tid = threadIdx.x;
    const int w = tid >> 6;
    const int l = tid & 63;
    const int lo4 = l & 15;
    const int g = l >> 4;
    // XCD swizzle: 1024 blocks = 16 hb x 64 qtiles; hb%8 == bid%8 == XCD
    const int bid = blockIdx.x;
    const int xcd = bid & 7;
    const int j = bid >> 3;
    const int hb = xcd + 8 * (j >> 6);
    const int q0 = (j & 63) * 64;
    const int qw = q0 + w * 16;       // this wave's 16 q-rows

    const _Float16* Qb = Qf + (size_t)hb * SEQ * HD;
    const _Float16* Kb = Kf + (size_t)hb * SEQ * HD;
    const _Float16* Vb = VT + (size_t)hb * HD * SEQ;

    const f16x8 Bq = *(const f16x8*)(Qb + (size_t)(qw + lo4) * HD + g * 8);

    // ---------- pass A: row sums of exp2(s), full k sweep ----------
    float ls = 0.f;
    for (int c = 0; c < 128; c++) {
        const int k0 = c * 32;
        #pragma unroll
        for (int s = 0; s < 2; s++) {
            f16x8 Ak = *(const f16x8*)(Kb + (size_t)(k0 + s * 16 + lo4) * HD + g * 8);
            f32x4 D = {0.f, 0.f, 0.f, 0.f};
            D = MFMA16(Ak, Bq, D);
            ls += exp2f(D[0]) + exp2f(D[1]) + exp2f(D[2]) + exp2f(D[3]);
        }
        if ((c & 3) == 3) __builtin_amdgcn_s_barrier();   // convergence only, no drain
    }
    ls += __shfl_xor(ls, 16, 64);
    ls += __shfl_xor(ls, 32, 64);
    const float inv = 1.0f / ls;      // wave-local: no LDS, no barrier needed

    // ---------- pass B: recompute, write probs, PV ----------
    f32x4 H0 = {0.f,0.f,0.f,0.f}, H1 = {0.f,0.f,0.f,0.f};
    float* ar = attn_out + ((size_t)hb * SEQ + qw + lo4) * SEQ;
    const int src0 = lo4 + ((g & 1) * 2) * 16;
    const int src1 = src0 + 16;

    for (int c = 0; c < 128; c++) {
        const int k0 = c * 32;
        uint_t w0[2], w1[2];
        #pragma unroll
        for (int s = 0; s < 2; s++) {
            f16x8 Ak = *(const f16x8*)(Kb + (size_t)(k0 + s * 16 + lo4) * HD + g * 8);
            f32x4 D = {0.f, 0.f, 0.f, 0.f};
            D = MFMA16(Ak, Bq, D);
            float p0 = exp2f(D[0]) * inv, p1 = exp2f(D[1]) * inv;
            float p2 = exp2f(D[2]) * inv, p3 = exp2f(D[3]) * inv;
            *(float4*)(ar + k0 + s * 16 + g * 4) = make_float4(p0, p1, p2, p3);
            w0[s] = pk16(p0, p1); w1[s] = pk16(p2, p3);
        }
        union { f16x8 v; uint_t u[4]; } P;
        {
            uint_t a, b2;
            a = __shfl(w0[0], src0, 64); b2 = __shfl(w0[1], src0, 64); P.u[0] = (g >= 2) ? b2 : a;
            a = __shfl(w1[0], src0, 64); b2 = __shfl(w1[1], src0, 64); P.u[1] = (g >= 2) ? b2 : a;
            a = __shfl(w0[0], src1, 64); b2 = __shfl(w0[1], src1, 64); P.u[2] = (g >= 2) ? b2 : a;
            a = __shfl(w1[0], src1, 64); b2 = __shfl(w1[1], src1, 64); P.u[3] = (g >= 2) ? b2 : a;
        }
        f16x8 Av0 = *(const f16x8*)(Vb + (size_t)lo4 * SEQ + k0 + g * 8);
        f16x8 Av1 = *(const f16x8*)(Vb + (size_t)(16 + lo4) * SEQ + k0 + g * 8);
        H0 = MFMA16(Av0, P.v, H0);
        H1 = MFMA16(Av1, P.v, H1);
        if ((c & 3) == 3) __builtin_amdgcn_s_barrier();   // convergence only, no drain
    }

    // ---------- epilogue: wave-complete H, direct f16x4 stores ----------
    _Float16* hrow = heads + ((size_t)hb * SEQ + qw + lo4) * HD;
    f16x4 h0, h1;
    #pragma unroll
    for (int r = 0; r < 4; r++) { h0[r] = (_Float16)H0[r]; h1[r] = (_Float16)H1[r]; }
    *(f16x4*)(hrow + g * 4) = h0;
    *(f16x4*)(hrow + 16 + g * 4) = h1;
}

// ---------------------------------------------------------------------------
// Kernel 3: output projection as MFMA GEMM.
// grid 128 x 256 thr: wave = 16 rows, all 256 out cols (16 col-tiles).
// out[r][o] = sum_he H[r][he] * (WoTh + WoTl)[o][he]
// ---------------------------------------------------------------------------
__global__ __launch_bounds__(256) void out_gemm_kernel(
    const _Float16* __restrict__ Hf,
    const _Float16* __restrict__ WoTh, const _Float16* __restrict__ WoTl,
    float* __restrict__ out)
{
    const int t = threadIdx.x, w = t >> 6, l = t & 63, lo4 = l & 15, g = l >> 4;
    const int r0 = blockIdx.x * 64 + w * 16;
    const int b = r0 >> 12;
    const int sb = r0 & (SEQ - 1);

    f16x8 A[8];
    #pragma unroll
    for (int kc = 0; kc < 8; kc++)
        A[kc] = *(const f16x8*)(Hf + (((size_t)(kc * BATCH + b)) * SEQ + sb + lo4) * HD + g * 8);

    for (int ct = 0; ct < 16; ct++) {
        f32x4 acc = {0.f, 0.f, 0.f, 0.f};
        const size_t woff = (size_t)(ct * 16 + lo4) * 256 + g * 8;
        #pragma unroll
        for (int kc = 0; kc < 8; kc++) {
            acc = MFMA16(A[kc], *(const f16x8*)(WoTh + woff + kc * 32), acc);
            acc = MFMA16(A[kc], *(const f16x8*)(WoTl + woff + kc * 32), acc);
        }
        #pragma unroll
        for (int r = 0; r < 4; r++)
            out[(size_t)(r0 + g * 4 + r) * 256 + ct * 16 + lo4] = acc[r];
    }
}

extern "C" void kernel_launch(void* const* d_in, const int* in_sizes, int n_in,
                              void* d_out, int out_size, void* d_ws, size_t ws_size,
                              hipStream_t stream) {
    const float* query = (const float*)d_in[0];
    const float* wq = (const float*)d_in[1];
    const float* wk = (const float*)d_in[2];
    const float* wv = (const float*)d_in[3];
    const float* wo = (const float*)d_in[4];
    float* out = (float*)d_out;
    float* attn_out = out + (size_t)BATCH * SEQ * EMB;

    _Float16* ws = (_Float16*)d_ws;
    const size_t nx  = (size_t)BATCH * SEQ * EMB;          // 2,097,152
    const size_t per = (size_t)HEADS * BATCH * SEQ * HD;   // 2,097,152
    _Float16* Xh   = ws;
    _Float16* Xl   = Xh + nx;
    _Float16* Wth  = Xl + nx;          // 196,608
    _Float16* Wtl  = Wth + 196608;
    _Float16* WoTh = Wtl + 196608;     // 65,536
    _Float16* WoTl = WoTh + 65536;
    _Float16* Qf   = WoTl + 65536;
    _Float16* Kf   = Qf + per;
    _Float16* VT   = Kf + per;
    _Float16* Hf   = VT + per;

    prep_x_kernel<<<(int)(nx / (256 * 8)), 256, 0, stream>>>(query, Xh, Xl);
    prep_w_kernel<<<256, 256, 0, stream>>>(wq, wk, wv, wo, Wth, Wtl, WoTh, WoTl);
    qkv_gemm_kernel<<<dim3((BATCH * SEQ) / 64, 3 * HEADS), 256, 0, stream>>>(
        Xh, Xl, Wth, Wtl, Qf, Kf, VT);
    attn_kernel<<<HEADS * BATCH * (SEQ / 64), 256, 0, stream>>>(
        Qf, Kf, VT, attn_out, Hf);
    out_gemm_kernel<<<(BATCH * SEQ) / 64, 256, 0, stream>>>(Hf, WoTh, WoTl, out);
}